// Round 2
// baseline (8557.443 us; speedup 1.0000x reference)
//
#include <hip/hip_runtime.h>
#include <math.h>

#define N_TOT 16384
#define C_TOT 1000
#define D_TOT 512

#define BN 128
#define BC 64
#define BD 16          // k-chunk staged per iteration
#define NROWS (BN + BC)  // 192 LDS rows of 16 floats

#define EPS_F 1e-8f
#define SCALE_F 0.04419417382415922f  // 1/sqrt(512)

#define GL_LDS(gp, lp)                                                        \
    __builtin_amdgcn_global_load_lds(                                         \
        (const __attribute__((address_space(1))) void*)(gp),                  \
        (__attribute__((address_space(3))) void*)(lp), 16, 0, 0)

// ---------------- fsq / csq precompute: one wave per row ----------------
__global__ __launch_bounds__(256)
void sq_kernel(const float* __restrict__ F, const float* __restrict__ Cc,
               float* __restrict__ sqout) {
    int gw   = (blockIdx.x * 256 + threadIdx.x) >> 6;
    int lane = threadIdx.x & 63;
    if (gw >= N_TOT + C_TOT) return;
    const float* src = (gw < N_TOT) ? (F + (size_t)gw * D_TOT)
                                    : (Cc + (size_t)(gw - N_TOT) * D_TOT);
    float4 a = *(const float4*)(src + lane * 4);
    float4 b = *(const float4*)(src + 256 + lane * 4);
    float acc = a.x * a.x;
    acc = fmaf(a.y, a.y, acc);
    acc = fmaf(a.z, a.z, acc);
    acc = fmaf(a.w, a.w, acc);
    acc = fmaf(b.x, b.x, acc);
    acc = fmaf(b.y, b.y, acc);
    acc = fmaf(b.z, b.z, acc);
    acc = fmaf(b.w, b.w, acc);
    #pragma unroll
    for (int off = 32; off > 0; off >>= 1)
        acc += __shfl_xor(acc, off);
    if (lane == 0) sqout[gw] = acc;
}

// ---------------- fused L1 / sq-sum main kernel ----------------
// LDS rows: [0..127] = F tile rows, [128..191] = C tile rows; each row = 16
// floats (one BD chunk). C rows are slot-swizzled: LDS slot s of row c holds
// global k-slot s ^ ((c>>2)&3), applied via the per-lane GLOBAL source addr.
__global__ __launch_bounds__(256, 4)
void dist_main(const float* __restrict__ F, const float* __restrict__ Cc,
               const float* __restrict__ sqbuf, float* __restrict__ out) {
    __shared__ float lds[2][NROWS * BD];

    const int tid = threadIdx.x;
    const int tx  = tid & 15;    // centroid dir: cols tx + 16*j
    const int ty  = tid >> 4;    // feature dir:  rows ty + 16*i
    const int c0  = blockIdx.x * BC;
    const int n0  = blockIdx.y * BN;

    // staging coords
    const int srow  = tid >> 2;        // 0..63
    const int sslot = tid & 3;         // 16B slot within row
    const int w16   = (tid >> 6) * 16; // wave's first staged row

    const float* fA = F + (size_t)(n0 + srow) * D_TOT + sslot * 4;
    const float* fB = fA + (size_t)64 * D_TOT;
    const int cswz  = sslot ^ ((srow >> 2) & 3);
    const float* cP = Cc + (size_t)(c0 + srow) * D_TOT + cswz * 4;
    const bool cok  = (c0 + srow) < C_TOT;

    float l1[8][4];
    float sq[8][4];
    #pragma unroll
    for (int i = 0; i < 8; ++i)
        #pragma unroll
        for (int j = 0; j < 4; ++j) { l1[i][j] = 0.f; sq[i][j] = 0.f; }

    // prologue: stage tile 0 into buf 0
    GL_LDS(fA, &lds[0][w16 * BD]);
    GL_LDS(fB, &lds[0][(64 + w16) * BD]);
    if (cok) GL_LDS(cP, &lds[0][(128 + w16) * BD]);
    __syncthreads();

    const int NT = D_TOT / BD;  // 32
    const int crs = (tx >> 2) & 3;  // reader-side c swizzle

    for (int t = 0; t < NT; ++t) {
        // issue next tile's loads (drained by the barrier below)
        if (t + 1 < NT) {
            const int nb = (t + 1) & 1;
            const int d1 = (t + 1) * BD;
            GL_LDS(fA + d1, &lds[nb][w16 * BD]);
            GL_LDS(fB + d1, &lds[nb][(64 + w16) * BD]);
            if (cok) GL_LDS(cP + d1, &lds[nb][(128 + w16) * BD]);
        }

        const float* lf = &lds[t & 1][0];
        #pragma unroll
        for (int q = 0; q < 4; ++q) {
            float cr[4][4];
            float fr[8][4];
            #pragma unroll
            for (int j = 0; j < 4; ++j)
                *(float4*)cr[j] = *(const float4*)
                    &lf[(128 + tx + 16 * j) * BD + ((q ^ crs) << 2)];
            #pragma unroll
            for (int i = 0; i < 8; ++i)
                *(float4*)fr[i] = *(const float4*)
                    &lf[((ty + 16 * i) << 4) + (q << 2)];
            #pragma unroll
            for (int i = 0; i < 8; ++i)
                #pragma unroll
                for (int j = 0; j < 4; ++j)
                    #pragma unroll
                    for (int k = 0; k < 4; ++k) {
                        float d = fr[i][k] - cr[j][k];
                        l1[i][j] += fabsf(d);
                        sq[i][j] = fmaf(d, d, sq[i][j]);
                    }
        }
        __syncthreads();
    }

    // ---------------- epilogue ----------------
    const float* fsq = sqbuf;
    const float* csq = sqbuf + N_TOT;

    float fs[8], fn[8];
    #pragma unroll
    for (int i = 0; i < 8; ++i) {
        fs[i] = fsq[n0 + ty + 16 * i];
        fn[i] = fmaxf(sqrtf(fs[i]), EPS_F);
    }
    float cs[4], cn[4];
    int   cc[4];
    #pragma unroll
    for (int j = 0; j < 4; ++j) {
        cc[j] = c0 + tx + 16 * j;
        cs[j] = (cc[j] < C_TOT) ? csq[cc[j]] : 0.f;
        cn[j] = fmaxf(sqrtf(cs[j]), EPS_F);
    }

    const size_t NC = (size_t)N_TOT * C_TOT;
    #pragma unroll
    for (int i = 0; i < 8; ++i) {
        const size_t rbase = (size_t)(n0 + ty + 16 * i) * C_TOT;
        #pragma unroll
        for (int j = 0; j < 4; ++j) {
            if (cc[j] < C_TOT) {
                float s   = sq[i][j];
                float dot = 0.5f * (fs[i] + cs[j] - s);
                size_t p  = rbase + cc[j];
                out[p]          = l1[i][j] * SCALE_F;
                out[NC + p]     = sqrtf(s) * SCALE_F;
                out[2 * NC + p] = dot * SCALE_F / (fn[i] * cn[j]);
            }
        }
    }
}

extern "C" void kernel_launch(void* const* d_in, const int* in_sizes, int n_in,
                              void* d_out, int out_size, void* d_ws, size_t ws_size,
                              hipStream_t stream) {
    const float* F  = (const float*)d_in[0];
    const float* Cc = (const float*)d_in[1];
    float* out   = (float*)d_out;
    float* sqbuf = (float*)d_ws;   // [N_TOT + C_TOT] floats

    int rows = N_TOT + C_TOT;
    sq_kernel<<<(rows + 3) / 4, 256, 0, stream>>>(F, Cc, sqbuf);
    dist_main<<<dim3(16, 128), 256, 0, stream>>>(F, Cc, sqbuf, out);
}

// Round 3
// 650.584 us; speedup vs baseline: 13.1535x; 13.1535x over previous
//
#include <hip/hip_runtime.h>
#include <math.h>

typedef float f32x4 __attribute__((ext_vector_type(4)));

#define N_TOT 16384
#define C_TOT 1000
#define D_TOT 512

#define BN 128
#define BC 64
#define BD 16           // k-chunk staged per iteration
#define NROWS (BN + BC) // 192 LDS rows of 16 floats

#define EPS_F 1e-8f
#define SCALE_F 0.04419417382415922f  // 1/sqrt(512)

#define GL_LDS(gp, lp)                                                        \
    __builtin_amdgcn_global_load_lds(                                         \
        (const __attribute__((address_space(1))) void*)(gp),                  \
        (__attribute__((address_space(3))) void*)(lp), 16, 0, 0)

// ---------------- fsq / csq precompute: one wave per row ----------------
__global__ __launch_bounds__(256)
void sq_kernel(const float* __restrict__ F, const float* __restrict__ Cc,
               float* __restrict__ sqout) {
    int gw   = (blockIdx.x * 256 + threadIdx.x) >> 6;
    int lane = threadIdx.x & 63;
    if (gw >= N_TOT + C_TOT) return;
    const float* src = (gw < N_TOT) ? (F + (size_t)gw * D_TOT)
                                    : (Cc + (size_t)(gw - N_TOT) * D_TOT);
    f32x4 a = *(const f32x4*)(src + lane * 4);
    f32x4 b = *(const f32x4*)(src + 256 + lane * 4);
    float acc = a[0] * a[0];
    acc = fmaf(a[1], a[1], acc);
    acc = fmaf(a[2], a[2], acc);
    acc = fmaf(a[3], a[3], acc);
    acc = fmaf(b[0], b[0], acc);
    acc = fmaf(b[1], b[1], acc);
    acc = fmaf(b[2], b[2], acc);
    acc = fmaf(b[3], b[3], acc);
    #pragma unroll
    for (int off = 32; off > 0; off >>= 1)
        acc += __shfl_xor(acc, off);
    if (lane == 0) sqout[gw] = acc;
}

// ---------------- fused L1 / sq-sum main kernel ----------------
// LDS rows: [0..127] = F tile rows, [128..191] = C tile rows; each row = 16
// floats (one BD chunk). C rows slot-swizzled on the GLOBAL source address
// (slot s of row c holds k-slot s ^ ((c>>2)&3)); reader applies same XOR.
// Measured R2: SQ_LDS_BANK_CONFLICT == 0 with this scheme.
__global__ __launch_bounds__(256)
void dist_main(const float* __restrict__ F, const float* __restrict__ Cc,
               const float* __restrict__ sqbuf, float* __restrict__ out) {
    __shared__ float lds[2][NROWS * BD];

    const int tid = threadIdx.x;
    const int tx  = tid & 15;    // centroid dir: cols tx + 16*j
    const int ty  = tid >> 4;    // feature dir:  rows ty + 16*i
    const int c0  = blockIdx.x * BC;
    const int n0  = blockIdx.y * BN;

    // staging coords
    const int srow  = tid >> 2;        // 0..63
    const int sslot = tid & 3;         // 16B slot within row
    const int w16   = (tid >> 6) * 16; // wave's first staged row

    const float* fA = F + (size_t)(n0 + srow) * D_TOT + sslot * 4;
    const float* fB = fA + (size_t)64 * D_TOT;
    const int cswz  = sslot ^ ((srow >> 2) & 3);
    const float* cP = Cc + (size_t)(c0 + srow) * D_TOT + cswz * 4;
    const bool cok  = (c0 + srow) < C_TOT;

    // accumulators: value-typed ext_vectors, never address-taken
    f32x4 l1v[8], sqv[8];
    #pragma unroll
    for (int i = 0; i < 8; ++i) {
        l1v[i] = (f32x4)(0.f);
        sqv[i] = (f32x4)(0.f);
    }

    // prologue: stage tile 0 into buf 0
    GL_LDS(fA, &lds[0][w16 * BD]);
    GL_LDS(fB, &lds[0][(64 + w16) * BD]);
    if (cok) GL_LDS(cP, &lds[0][(128 + w16) * BD]);
    __syncthreads();

    const int NT  = D_TOT / BD;     // 32
    const int crs = (tx >> 2) & 3;  // reader-side c swizzle

    for (int t = 0; t < NT; ++t) {
        if (t + 1 < NT) {
            const int nb = (t + 1) & 1;
            const int d1 = (t + 1) * BD;
            GL_LDS(fA + d1, &lds[nb][w16 * BD]);
            GL_LDS(fB + d1, &lds[nb][(64 + w16) * BD]);
            if (cok) GL_LDS(cP + d1, &lds[nb][(128 + w16) * BD]);
        }

        const float* lf = &lds[t & 1][0];
        #pragma unroll
        for (int q = 0; q < 4; ++q) {
            const int cq = (q ^ crs) << 2;
            f32x4 cv0 = *(const f32x4*)&lf[(128 + tx) * BD + cq];
            f32x4 cv1 = *(const f32x4*)&lf[(128 + tx + 16) * BD + cq];
            f32x4 cv2 = *(const f32x4*)&lf[(128 + tx + 32) * BD + cq];
            f32x4 cv3 = *(const f32x4*)&lf[(128 + tx + 48) * BD + cq];
            #pragma unroll
            for (int i = 0; i < 8; ++i) {
                f32x4 fv = *(const f32x4*)&lf[((ty + 16 * i) << 4) + (q << 2)];
                #pragma unroll
                for (int k = 0; k < 4; ++k) {
                    float fk = fv[k];
                    float d0 = fk - cv0[k];
                    float d1_ = fk - cv1[k];
                    float d2 = fk - cv2[k];
                    float d3 = fk - cv3[k];
                    l1v[i][0] += fabsf(d0);
                    l1v[i][1] += fabsf(d1_);
                    l1v[i][2] += fabsf(d2);
                    l1v[i][3] += fabsf(d3);
                    sqv[i][0] = fmaf(d0, d0, sqv[i][0]);
                    sqv[i][1] = fmaf(d1_, d1_, sqv[i][1]);
                    sqv[i][2] = fmaf(d2, d2, sqv[i][2]);
                    sqv[i][3] = fmaf(d3, d3, sqv[i][3]);
                }
            }
        }
        __syncthreads();
    }

    // ---------------- epilogue ----------------
    const float* fsq = sqbuf;
    const float* csq = sqbuf + N_TOT;
    const int cbase = c0 + tx;

    f32x4 csv, cnv;
    #pragma unroll
    for (int j = 0; j < 4; ++j) {
        int c = cbase + 16 * j;
        float v = (c < C_TOT) ? csq[c] : 0.f;
        csv[j] = v;
        cnv[j] = fmaxf(sqrtf(v), EPS_F);
    }

    const size_t NC = (size_t)N_TOT * C_TOT;
    #pragma unroll
    for (int i = 0; i < 8; ++i) {
        const int n = n0 + ty + 16 * i;
        const float fs = fsq[n];
        const float fn = fmaxf(sqrtf(fs), EPS_F);
        const size_t rbase = (size_t)n * C_TOT;
        #pragma unroll
        for (int j = 0; j < 4; ++j) {
            const int c = cbase + 16 * j;
            if (c < C_TOT) {
                float s   = sqv[i][j];
                float dot = 0.5f * (fs + csv[j] - s);
                size_t p  = rbase + c;
                out[p]          = l1v[i][j] * SCALE_F;
                out[NC + p]     = sqrtf(s) * SCALE_F;
                out[2 * NC + p] = dot * SCALE_F / (fn * cnv[j]);
            }
        }
    }
}

extern "C" void kernel_launch(void* const* d_in, const int* in_sizes, int n_in,
                              void* d_out, int out_size, void* d_ws, size_t ws_size,
                              hipStream_t stream) {
    const float* F  = (const float*)d_in[0];
    const float* Cc = (const float*)d_in[1];
    float* out   = (float*)d_out;
    float* sqbuf = (float*)d_ws;   // [N_TOT + C_TOT] floats

    int rows = N_TOT + C_TOT;
    sq_kernel<<<(rows + 3) / 4, 256, 0, stream>>>(F, Cc, sqbuf);
    dist_main<<<dim3(16, 128), 256, 0, stream>>>(F, Cc, sqbuf, out);
}